// Round 1
// baseline (111.995 us; speedup 1.0000x reference)
//
#include <hip/hip_runtime.h>
#include <math.h>

#define EPSB 1e-5f

constexpr int NN = 32, CIN = 256, HH = 56, WW = 56, HW = HH * WW; // 3136
constexpr int CMID = 16, NB = 4, CBOX = 64, COUT = 256;

// workspace offsets (in floats)
constexpr size_t WS_W1T  = 0;                         // [CIN][CMID] folded w1*inv1
constexpr size_t WS_B1F  = WS_W1T + (size_t)CIN * CMID;   // 16
constexpr size_t WS_W3T  = WS_B1F + CMID;                 // [CBOX][COUT]
constexpr size_t WS_INV3 = WS_W3T + (size_t)CBOX * COUT;  // 256
constexpr size_t WS_B3F  = WS_INV3 + COUT;                // 256
constexpr size_t WS_OUT1 = WS_B3F + COUT;                 // N*CMID*HW
constexpr size_t WS_OUT2 = WS_OUT1 + (size_t)NN * CMID * HW; // N*CBOX*HW

__global__ __launch_bounds__(256) void k_prep(
    const float* __restrict__ w1, const float* __restrict__ g1,
    const float* __restrict__ b1, const float* __restrict__ m1,
    const float* __restrict__ v1,
    const float* __restrict__ w3, const float* __restrict__ g3,
    const float* __restrict__ b3, const float* __restrict__ m3,
    const float* __restrict__ v3, float* __restrict__ ws) {
  int t = threadIdx.x;
  for (int idx = t; idx < CIN * CMID; idx += 256) {
    int ci = idx >> 4, c = idx & 15;
    float inv = g1[c] / sqrtf(v1[c] + EPSB);
    ws[WS_W1T + idx] = w1[c * CIN + ci] * inv;
  }
  if (t < CMID) {
    float inv = g1[t] / sqrtf(v1[t] + EPSB);
    ws[WS_B1F + t] = b1[t] - m1[t] * inv;
  }
  for (int idx = t; idx < CBOX * COUT; idx += 256) {
    int k = idx >> 8, o = idx & 255;
    ws[WS_W3T + idx] = w3[o * CBOX + k];
  }
  {
    float inv = g3[t] / sqrtf(v3[t] + EPSB);
    ws[WS_INV3 + t] = inv;
    ws[WS_B3F + t] = b3[t] - m3[t] * inv;
  }
}

// conv1 (256->16) + BN1 + ReLU. Block: 64 pixels, 4-way ci split.
__global__ __launch_bounds__(256) void k1(const float* __restrict__ x,
                                          const float* __restrict__ ws_c,
                                          float* __restrict__ out1) {
  __shared__ float red[4 * 64 * 17]; // [kq][pix][17] padded
  int bid = blockIdx.x;              // NN*49
  int n = bid / 49, hwb = (bid % 49) * 64;
  int tid = threadIdx.x;
  int lane = tid & 63;
  int kq = tid >> 6;
  int kq_u = __builtin_amdgcn_readfirstlane(tid) >> 6;

  const float* xb = x + (size_t)n * CIN * HW + hwb + lane;
  const float* w1t = ws_c + WS_W1T;
  float acc[CMID];
#pragma unroll
  for (int c = 0; c < CMID; ++c) acc[c] = 0.f;

  int ci0 = kq_u * 64;
#pragma unroll 8
  for (int i = 0; i < 64; ++i) {
    int ci = ci0 + i;
    float xv = xb[(size_t)ci * HW];
    const float* wr = w1t + ci * CMID;
#pragma unroll
    for (int c = 0; c < CMID; ++c) acc[c] = fmaf(xv, wr[c], acc[c]);
  }
#pragma unroll
  for (int c = 0; c < CMID; ++c) red[kq * 1088 + lane * 17 + c] = acc[c];
  __syncthreads();

  const float* b1f = ws_c + WS_B1F;
#pragma unroll
  for (int j = 0; j < 4; ++j) {
    int o = tid + j * 256;      // o = c*64 + pix
    int c = o >> 6, pix = o & 63;
    float v = red[pix * 17 + c] + red[1088 + pix * 17 + c] +
              red[2176 + pix * 17 + c] + red[3264 + pix * 17 + c];
    v += b1f[c];
    out1[((size_t)n * CMID + c) * HW + hwb + pix] = fmaxf(v, 0.f);
  }
}

__device__ __forceinline__ float bilin(const float* __restrict__ sI, float y, float x) {
  int iy = min((int)y, 55);
  int ix = min((int)x, 55);
  float ty = y - (float)iy;
  float tx = x - (float)ix;
  const float* r = sI + iy * 57 + ix;
  float a = r[0], b = r[1], cc = r[57], d = r[58];
  float g1v = a * (1.f - ty) + cc * ty;
  float g2v = b * (1.f - ty) + d * ty;
  return g1v * (1.f - tx) + g2v * tx;
}

// integral image + 4 boxes + BN2 + ReLU. One block per (n, c).
__global__ __launch_bounds__(512) void k2(
    const float* __restrict__ out1,
    const float* __restrict__ y_min, const float* __restrict__ y_max,
    const float* __restrict__ x_min, const float* __restrict__ x_max,
    const float* __restrict__ g2, const float* __restrict__ b2,
    const float* __restrict__ m2, const float* __restrict__ v2,
    float* __restrict__ out2) {
  __shared__ float sI[57 * 57];
  int bid = blockIdx.x;            // NN*CMID = 512
  int n = bid >> 4, c = bid & 15;
  int tid = threadIdx.x;

  for (int idx = tid; idx < 57 * 57; idx += 512) sI[idx] = 0.f;
  __syncthreads();
  const float* src = out1 + ((size_t)n * CMID + c) * HW;
  for (int idx = tid; idx < HW; idx += 512) {
    int h = idx / 56, w = idx - h * 56;
    sI[(h + 1) * 57 + (w + 1)] = src[idx];
  }
  __syncthreads();
  if (tid < 56) { // row cumsum (row tid+1), chain kept in register
    float run = 0.f;
    int base = (tid + 1) * 57;
    for (int w = 1; w <= 56; ++w) { run += sI[base + w]; sI[base + w] = run; }
  }
  __syncthreads();
  if (tid < 56) { // col cumsum (col tid+1)
    float run = 0.f;
    int col = tid + 1;
    for (int h = 1; h <= 56; ++h) { run += sI[h * 57 + col]; sI[h * 57 + col] = run; }
  }
  __syncthreads();

  // preload per-box params (uniform)
  float pymn[NB], pymx[NB], pxmn[NB], pxmx[NB], pinv[NB], pbi[NB], prar[NB];
#pragma unroll
  for (int b = 0; b < NB; ++b) {
    int cb = c * NB + b;
    pymn[b] = y_min[cb]; pymx[b] = y_max[cb];
    pxmn[b] = x_min[cb]; pxmx[b] = x_max[cb];
    float inv = g2[cb] / sqrtf(v2[cb] + EPSB);
    pinv[b] = inv;
    pbi[b] = b2[cb] - m2[cb] * inv;
    prar[b] = 1.f / ((pymx[b] - pymn[b] + 1.f) * (pxmx[b] - pxmn[b] + 1.f));
  }
  float* dst0 = out2 + ((size_t)n * CBOX + c * NB) * HW;

  for (int p = tid; p < HW; p += 512) {
    int h = p / 56, w = p - h * 56;
    float fh = (float)h, fw = (float)w;
#pragma unroll
    for (int b = 0; b < NB; ++b) {
      float y1 = fminf(fmaxf(fh + pymn[b], 0.f), 56.f);
      float y2 = fminf(fmaxf(fh + pymx[b] + 1.f, 0.f), 56.f);
      float x1 = fminf(fmaxf(fw + pxmn[b], 0.f), 56.f);
      float x2 = fminf(fmaxf(fw + pxmx[b] + 1.f, 0.f), 56.f);
      float S = bilin(sI, y2, x2) - bilin(sI, y2, x1) - bilin(sI, y1, x2) + bilin(sI, y1, x1);
      float val = S * prar[b] * pinv[b] + pbi[b];
      dst0[(size_t)b * HW + p] = fmaxf(val, 0.f);
    }
  }
}

// conv3 (64->256) + BN3 + residual + ReLU. Block: 64 pixels x 256 outputs.
__global__ __launch_bounds__(512) void k3(const float* __restrict__ out2,
                                          const float* __restrict__ ws_c,
                                          const float* __restrict__ x,
                                          float* __restrict__ out) {
  __shared__ float tile[CBOX * 64]; // [k][pix]
  int bid = blockIdx.x;             // NN*49
  int n = bid / 49, hwb = (bid % 49) * 64;
  int tid = threadIdx.x;

  const float* src = out2 + (size_t)n * CBOX * HW + hwb;
  for (int idx = tid; idx < CBOX * 64; idx += 512) {
    int k = idx >> 6, pix = idx & 63;
    tile[idx] = src[(size_t)k * HW + pix];
  }
  __syncthreads();

  int lane = tid & 63;
  int og = __builtin_amdgcn_readfirstlane(tid) >> 6; // 0..7, SGPR
  const float* w3t = ws_c + WS_W3T + og * 32;        // [k][o] layout
  float acc[32];
#pragma unroll
  for (int j = 0; j < 32; ++j) acc[j] = 0.f;

#pragma unroll 4
  for (int k = 0; k < CBOX; ++k) {
    float a = tile[k * 64 + lane];
    const float* wr = w3t + k * COUT;
#pragma unroll
    for (int j = 0; j < 32; ++j) acc[j] = fmaf(a, wr[j], acc[j]);
  }

  const float* inv3 = ws_c + WS_INV3;
  const float* b3f = ws_c + WS_B3F;
  size_t obase = (size_t)n * COUT * HW + hwb + lane;
#pragma unroll
  for (int j = 0; j < 32; ++j) {
    int o = og * 32 + j;
    float v = acc[j] * inv3[o] + b3f[o];
    size_t idx = obase + (size_t)o * HW;
    v += x[idx];
    out[idx] = fmaxf(v, 0.f);
  }
}

extern "C" void kernel_launch(void* const* d_in, const int* in_sizes, int n_in,
                              void* d_out, int out_size, void* d_ws, size_t ws_size,
                              hipStream_t stream) {
  const float* x   = (const float*)d_in[0];
  const float* w1  = (const float*)d_in[1];
  const float* g1  = (const float*)d_in[2];
  const float* b1  = (const float*)d_in[3];
  const float* m1  = (const float*)d_in[4];
  const float* v1  = (const float*)d_in[5];
  const float* ymn = (const float*)d_in[6];
  const float* ymx = (const float*)d_in[7];
  const float* xmn = (const float*)d_in[8];
  const float* xmx = (const float*)d_in[9];
  const float* g2  = (const float*)d_in[10];
  const float* b2  = (const float*)d_in[11];
  const float* m2  = (const float*)d_in[12];
  const float* v2  = (const float*)d_in[13];
  const float* w3  = (const float*)d_in[14];
  const float* g3  = (const float*)d_in[15];
  const float* b3  = (const float*)d_in[16];
  const float* m3  = (const float*)d_in[17];
  const float* v3  = (const float*)d_in[18];

  float* ws  = (float*)d_ws;
  float* out = (float*)d_out;

  k_prep<<<1, 256, 0, stream>>>(w1, g1, b1, m1, v1, w3, g3, b3, m3, v3, ws);
  k1<<<NN * 49, 256, 0, stream>>>(x, ws, ws + WS_OUT1);
  k2<<<NN * CMID, 512, 0, stream>>>(ws + WS_OUT1, ymn, ymx, xmn, xmx,
                                    g2, b2, m2, v2, ws + WS_OUT2);
  k3<<<NN * 49, 512, 0, stream>>>(ws + WS_OUT2, ws, x, out);
}

// Round 2
// 91.224 us; speedup vs baseline: 1.2277x; 1.2277x over previous
//
#include <hip/hip_runtime.h>
#include <hip/hip_bf16.h>
#include <math.h>

#define EPSB 1e-5f

constexpr int NN = 32, CIN = 256, HH = 56, WW = 56, HW = HH * WW; // 3136
constexpr int CMID = 16, NB = 4, CBOX = 64, COUT = 256;

typedef __attribute__((ext_vector_type(8))) short short8;
typedef __attribute__((ext_vector_type(4))) float f32x4;

// workspace offsets (in floats)
constexpr size_t WS_W1T   = 0;                             // [CIN][CMID] folded
constexpr size_t WS_B1F   = WS_W1T + (size_t)CIN * CMID;   // 16
constexpr size_t WS_INV3  = WS_B1F + CMID;                 // 256
constexpr size_t WS_B3F   = WS_INV3 + COUT;                // 256
constexpr size_t WS_OUT1  = WS_B3F + COUT;                 // N*CMID*HW f32
constexpr size_t WS_W3B   = WS_OUT1 + (size_t)NN * CMID * HW;  // 64*256 bf16 (8192 f32 slots)
constexpr size_t WS_OUT2B = WS_W3B + (size_t)CBOX * COUT / 2;  // N*64*HW bf16

__global__ __launch_bounds__(256) void k_prep(
    const float* __restrict__ w1, const float* __restrict__ g1,
    const float* __restrict__ b1, const float* __restrict__ m1,
    const float* __restrict__ v1,
    const float* __restrict__ w3, const float* __restrict__ g3,
    const float* __restrict__ b3, const float* __restrict__ m3,
    const float* __restrict__ v3, float* __restrict__ ws) {
  int t = threadIdx.x;
  for (int idx = t; idx < CIN * CMID; idx += 256) {
    int ci = idx >> 4, c = idx & 15;
    float inv = g1[c] / sqrtf(v1[c] + EPSB);
    ws[WS_W1T + idx] = w1[c * CIN + ci] * inv;
  }
  if (t < CMID) {
    float inv = g1[t] / sqrtf(v1[t] + EPSB);
    ws[WS_B1F + t] = b1[t] - m1[t] * inv;
  }
  // w3 -> bf16, layout [o][k] (same as input layout)
  __hip_bfloat16* w3b = (__hip_bfloat16*)(ws + WS_W3B);
  for (int idx = t; idx < COUT * CBOX; idx += 256) {
    w3b[idx] = __float2bfloat16(w3[idx]);
  }
  {
    float inv = g3[t] / sqrtf(v3[t] + EPSB);
    ws[WS_INV3 + t] = inv;
    ws[WS_B3F + t] = b3[t] - m3[t] * inv;
  }
}

// conv1 (256->16) + BN1 + ReLU. Block: 64 pixels, 4-way ci split.
__global__ __launch_bounds__(256) void k1(const float* __restrict__ x,
                                          const float* __restrict__ ws_c,
                                          float* __restrict__ out1) {
  __shared__ float red[4 * 64 * 17]; // [kq][pix][17] padded
  int bid = blockIdx.x;              // NN*49
  int n = bid / 49, hwb = (bid % 49) * 64;
  int tid = threadIdx.x;
  int lane = tid & 63;
  int kq = tid >> 6;
  int kq_u = __builtin_amdgcn_readfirstlane(tid) >> 6;

  const float* xb = x + (size_t)n * CIN * HW + hwb + lane;
  const float* w1t = ws_c + WS_W1T;
  float acc[CMID];
#pragma unroll
  for (int c = 0; c < CMID; ++c) acc[c] = 0.f;

  int ci0 = kq_u * 64;
#pragma unroll 8
  for (int i = 0; i < 64; ++i) {
    int ci = ci0 + i;
    float xv = xb[(size_t)ci * HW];
    const float* wr = w1t + ci * CMID;
#pragma unroll
    for (int c = 0; c < CMID; ++c) acc[c] = fmaf(xv, wr[c], acc[c]);
  }
#pragma unroll
  for (int c = 0; c < CMID; ++c) red[kq * 1088 + lane * 17 + c] = acc[c];
  __syncthreads();

  const float* b1f = ws_c + WS_B1F;
#pragma unroll
  for (int j = 0; j < 4; ++j) {
    int o = tid + j * 256;      // o = c*64 + pix
    int c = o >> 6, pix = o & 63;
    float v = red[pix * 17 + c] + red[1088 + pix * 17 + c] +
              red[2176 + pix * 17 + c] + red[3264 + pix * 17 + c];
    v += b1f[c];
    out1[((size_t)n * CMID + c) * HW + hwb + pix] = fmaxf(v, 0.f);
  }
}

__device__ __forceinline__ float bilin(const float* __restrict__ sI, float y, float x) {
  int iy = min((int)y, 55);
  int ix = min((int)x, 55);
  float ty = y - (float)iy;
  float tx = x - (float)ix;
  const float* r = sI + iy * 57 + ix;
  float a = r[0], b = r[1], cc = r[57], d = r[58];
  float g1v = a * (1.f - ty) + cc * ty;
  float g2v = b * (1.f - ty) + d * ty;
  return g1v * (1.f - tx) + g2v * tx;
}

// integral image + 4 boxes + BN2 + ReLU -> bf16. One block per (n, c).
__global__ __launch_bounds__(512) void k2(
    const float* __restrict__ out1,
    const float* __restrict__ y_min, const float* __restrict__ y_max,
    const float* __restrict__ x_min, const float* __restrict__ x_max,
    const float* __restrict__ g2, const float* __restrict__ b2,
    const float* __restrict__ m2, const float* __restrict__ v2,
    __hip_bfloat16* __restrict__ out2b) {
  __shared__ float sI[57 * 57];
  int bid = blockIdx.x;            // NN*CMID = 512
  int n = bid >> 4, c = bid & 15;
  int tid = threadIdx.x;

  for (int idx = tid; idx < 57 * 57; idx += 512) sI[idx] = 0.f;
  __syncthreads();
  const float* src = out1 + ((size_t)n * CMID + c) * HW;
  for (int idx = tid; idx < HW; idx += 512) {
    int h = idx / 56, w = idx - h * 56;
    sI[(h + 1) * 57 + (w + 1)] = src[idx];
  }
  __syncthreads();
  if (tid < 56) { // row cumsum (row tid+1)
    float run = 0.f;
    int base = (tid + 1) * 57;
    for (int w = 1; w <= 56; ++w) { run += sI[base + w]; sI[base + w] = run; }
  }
  __syncthreads();
  if (tid < 56) { // col cumsum (col tid+1)
    float run = 0.f;
    int col = tid + 1;
    for (int h = 1; h <= 56; ++h) { run += sI[h * 57 + col]; sI[h * 57 + col] = run; }
  }
  __syncthreads();

  float pymn[NB], pymx[NB], pxmn[NB], pxmx[NB], pinv[NB], pbi[NB], prar[NB];
#pragma unroll
  for (int b = 0; b < NB; ++b) {
    int cb = c * NB + b;
    pymn[b] = y_min[cb]; pymx[b] = y_max[cb];
    pxmn[b] = x_min[cb]; pxmx[b] = x_max[cb];
    float inv = g2[cb] / sqrtf(v2[cb] + EPSB);
    pinv[b] = inv;
    pbi[b] = b2[cb] - m2[cb] * inv;
    prar[b] = 1.f / ((pymx[b] - pymn[b] + 1.f) * (pxmx[b] - pxmn[b] + 1.f));
  }
  __hip_bfloat16* dst0 = out2b + ((size_t)n * CBOX + c * NB) * HW;

  for (int p = tid; p < HW; p += 512) {
    int h = p / 56, w = p - h * 56;
    float fh = (float)h, fw = (float)w;
#pragma unroll
    for (int b = 0; b < NB; ++b) {
      float y1 = fminf(fmaxf(fh + pymn[b], 0.f), 56.f);
      float y2 = fminf(fmaxf(fh + pymx[b] + 1.f, 0.f), 56.f);
      float x1 = fminf(fmaxf(fw + pxmn[b], 0.f), 56.f);
      float x2 = fminf(fmaxf(fw + pxmx[b] + 1.f, 0.f), 56.f);
      float S = bilin(sI, y2, x2) - bilin(sI, y2, x1) - bilin(sI, y1, x2) + bilin(sI, y1, x1);
      float val = S * prar[b] * pinv[b] + pbi[b];
      dst0[(size_t)b * HW + p] = __float2bfloat16(fmaxf(val, 0.f));
    }
  }
}

// conv3 (64->256) via bf16 MFMA + BN3 + residual + ReLU.
// Block: 512 thr (8 waves), 64 pixels x 256 outputs. Wave w -> o in [w*32, w*32+32).
__global__ __launch_bounds__(512) void k3(
    const __hip_bfloat16* __restrict__ out2b,
    const __hip_bfloat16* __restrict__ w3b,
    const float* __restrict__ inv3, const float* __restrict__ b3f,
    const float* __restrict__ x, float* __restrict__ out) {
  __shared__ __hip_bfloat16 T[64][72]; // [pix][k], 144B rows (bank-rotating)
  int bid = blockIdx.x;                // NN*49
  int n = bid / 49, hwb = (bid % 49) * 64;
  int tid = threadIdx.x;
  int l = tid & 63, w = tid >> 6;

  // stage out2 tile transposed: lane l = k-row, wave w = pixel group (8 pix)
  {
    const __hip_bfloat16* src = out2b + ((size_t)n * CBOX + l) * HW + hwb + w * 8;
    short8 v = *reinterpret_cast<const short8*>(src);
    const __hip_bfloat16* vp = (const __hip_bfloat16*)&v;
#pragma unroll
    for (int i = 0; i < 8; ++i) T[w * 8 + i][l] = vp[i];
  }

  // A-frags (w3, [o][k]): lane l holds A[o0 + (l&15)][k0 + (l>>4)*8 + j]
  short8 afrag[2][2];
#pragma unroll
  for (int ot = 0; ot < 2; ++ot)
#pragma unroll
    for (int kh = 0; kh < 2; ++kh) {
      int o = w * 32 + ot * 16 + (l & 15);
      int k0 = kh * 32 + (l >> 4) * 8;
      afrag[ot][kh] = *reinterpret_cast<const short8*>(w3b + o * CBOX + k0);
    }

  __syncthreads();

  // B-frags from LDS: lane l holds B[k0 + (l>>4)*8 + j][pixb + (l&15)]
  short8 bfrag[4][2];
#pragma unroll
  for (int pt = 0; pt < 4; ++pt)
#pragma unroll
    for (int kh = 0; kh < 2; ++kh) {
      int pix = pt * 16 + (l & 15);
      int k0 = kh * 32 + (l >> 4) * 8;
      bfrag[pt][kh] = *reinterpret_cast<const short8*>(&T[pix][k0]);
    }

  f32x4 acc[2][4];
#pragma unroll
  for (int ot = 0; ot < 2; ++ot)
#pragma unroll
    for (int pt = 0; pt < 4; ++pt) acc[ot][pt] = (f32x4)(0.f);

#pragma unroll
  for (int ot = 0; ot < 2; ++ot)
#pragma unroll
    for (int pt = 0; pt < 4; ++pt) {
      acc[ot][pt] = __builtin_amdgcn_mfma_f32_16x16x32_bf16(
          afrag[ot][0], bfrag[pt][0], acc[ot][pt], 0, 0, 0);
      acc[ot][pt] = __builtin_amdgcn_mfma_f32_16x16x32_bf16(
          afrag[ot][1], bfrag[pt][1], acc[ot][pt], 0, 0, 0);
    }

  // epilogue: D row = o = o0 + (l>>4)*4 + j, col = pix = pt*16 + (l&15)
  size_t nbase = (size_t)n * COUT * HW + hwb;
#pragma unroll
  for (int ot = 0; ot < 2; ++ot) {
#pragma unroll
    for (int j = 0; j < 4; ++j) {
      int o = w * 32 + ot * 16 + (l >> 4) * 4 + j;
      float iv = inv3[o], bb = b3f[o];
      size_t rowbase = nbase + (size_t)o * HW;
#pragma unroll
      for (int pt = 0; pt < 4; ++pt) {
        int pix = pt * 16 + (l & 15);
        float v = acc[ot][pt][j] * iv + bb + x[rowbase + pix];
        out[rowbase + pix] = fmaxf(v, 0.f);
      }
    }
  }
}

extern "C" void kernel_launch(void* const* d_in, const int* in_sizes, int n_in,
                              void* d_out, int out_size, void* d_ws, size_t ws_size,
                              hipStream_t stream) {
  const float* x   = (const float*)d_in[0];
  const float* w1  = (const float*)d_in[1];
  const float* g1  = (const float*)d_in[2];
  const float* b1  = (const float*)d_in[3];
  const float* m1  = (const float*)d_in[4];
  const float* v1  = (const float*)d_in[5];
  const float* ymn = (const float*)d_in[6];
  const float* ymx = (const float*)d_in[7];
  const float* xmn = (const float*)d_in[8];
  const float* xmx = (const float*)d_in[9];
  const float* g2  = (const float*)d_in[10];
  const float* b2  = (const float*)d_in[11];
  const float* m2  = (const float*)d_in[12];
  const float* v2  = (const float*)d_in[13];
  const float* w3  = (const float*)d_in[14];
  const float* g3  = (const float*)d_in[15];
  const float* b3  = (const float*)d_in[16];
  const float* m3  = (const float*)d_in[17];
  const float* v3  = (const float*)d_in[18];

  float* ws  = (float*)d_ws;
  float* out = (float*)d_out;
  __hip_bfloat16* w3b   = (__hip_bfloat16*)(ws + WS_W3B);
  __hip_bfloat16* out2b = (__hip_bfloat16*)(ws + WS_OUT2B);

  k_prep<<<1, 256, 0, stream>>>(w1, g1, b1, m1, v1, w3, g3, b3, m3, v3, ws);
  k1<<<NN * 49, 256, 0, stream>>>(x, ws, ws + WS_OUT1);
  k2<<<NN * CMID, 512, 0, stream>>>(ws + WS_OUT1, ymn, ymx, xmn, xmx,
                                    g2, b2, m2, v2, out2b);
  k3<<<NN * 49, 512, 0, stream>>>(out2b, w3b, ws + WS_INV3, ws + WS_B3F, x, out);
}

// Round 3
// 90.110 us; speedup vs baseline: 1.2429x; 1.0124x over previous
//
#include <hip/hip_runtime.h>
#include <hip/hip_bf16.h>
#include <math.h>

#define EPSB 1e-5f

constexpr int NN = 32, CIN = 256, HH = 56, WW = 56, HW = HH * WW; // 3136
constexpr int CMID = 16, NB = 4, CBOX = 64, COUT = 256;

typedef __attribute__((ext_vector_type(8))) short short8;
typedef __attribute__((ext_vector_type(4))) float f32x4;

// workspace offsets (in floats)
constexpr size_t WS_OUT1  = 0;                                  // N*CMID*HW f32
constexpr size_t WS_OUT2B = WS_OUT1 + (size_t)NN * CMID * HW;   // N*64*HW bf16

// conv1 (256->16) + BN1 + ReLU. Block: 64 pixels, 4-way ci split.
// w1 folding done in-block (LDS), no prep kernel.
__global__ __launch_bounds__(256) void k1(const float* __restrict__ x,
                                          const float* __restrict__ w1,
                                          const float* __restrict__ g1,
                                          const float* __restrict__ b1,
                                          const float* __restrict__ m1,
                                          const float* __restrict__ v1,
                                          float* __restrict__ out1) {
  __shared__ float w1s[CIN][CMID];   // 16 KB, folded weights [ci][c]
  __shared__ float red[4 * 64 * 17]; // 17.4 KB [kq][pix][17]
  int bid = blockIdx.x;              // NN*49
  int n = bid / 49, hwb = (bid % 49) * 64;
  int tid = threadIdx.x;
  int lane = tid & 63;
  int kq = tid >> 6;
  int kq_u = __builtin_amdgcn_readfirstlane(tid) >> 6;

  // fold: thread t owns ci=t, all 16 c (coalesced w1 reads per c-row)
#pragma unroll
  for (int c = 0; c < CMID; ++c) {
    float inv = g1[c] / sqrtf(v1[c] + EPSB);
    w1s[tid][c] = w1[c * CIN + tid] * inv;
  }
  __syncthreads();

  const float* xb = x + (size_t)n * CIN * HW + hwb + lane;
  float acc[CMID];
#pragma unroll
  for (int c = 0; c < CMID; ++c) acc[c] = 0.f;

  int ci0 = kq_u * 64;
#pragma unroll 8
  for (int i = 0; i < 64; ++i) {
    int ci = ci0 + i;
    float xv = xb[(size_t)ci * HW];
    const f32x4* wv = (const f32x4*)&w1s[ci][0]; // wave-uniform -> broadcast
#pragma unroll
    for (int q = 0; q < 4; ++q) {
      f32x4 wq = wv[q];
      acc[q * 4 + 0] = fmaf(xv, wq.x, acc[q * 4 + 0]);
      acc[q * 4 + 1] = fmaf(xv, wq.y, acc[q * 4 + 1]);
      acc[q * 4 + 2] = fmaf(xv, wq.z, acc[q * 4 + 2]);
      acc[q * 4 + 3] = fmaf(xv, wq.w, acc[q * 4 + 3]);
    }
  }
#pragma unroll
  for (int c = 0; c < CMID; ++c) red[kq * 1088 + lane * 17 + c] = acc[c];
  __syncthreads();

#pragma unroll
  for (int j = 0; j < 4; ++j) {
    int o = tid + j * 256;      // o = c*64 + pix; c is wave-uniform
    int c = o >> 6, pix = o & 63;
    float v = red[pix * 17 + c] + red[1088 + pix * 17 + c] +
              red[2176 + pix * 17 + c] + red[3264 + pix * 17 + c];
    float inv = g1[c] / sqrtf(v1[c] + EPSB);
    v += b1[c] - m1[c] * inv;
    out1[((size_t)n * CMID + c) * HW + hwb + pix] = fmaxf(v, 0.f);
  }
}

__device__ __forceinline__ float bilin(const float* __restrict__ sI, float y, float x) {
  int iy = min((int)y, 55);
  int ix = min((int)x, 55);
  float ty = y - (float)iy;
  float tx = x - (float)ix;
  const float* r = sI + iy * 57 + ix;
  float a = r[0], b = r[1], cc = r[57], d = r[58];
  float g1v = a * (1.f - ty) + cc * ty;
  float g2v = b * (1.f - ty) + d * ty;
  return g1v * (1.f - tx) + g2v * tx;
}

// integral image (wave-parallel scans) + 4 boxes + BN2 + ReLU -> bf16.
__global__ __launch_bounds__(512) void k2(
    const float* __restrict__ out1,
    const float* __restrict__ y_min, const float* __restrict__ y_max,
    const float* __restrict__ x_min, const float* __restrict__ x_max,
    const float* __restrict__ g2, const float* __restrict__ b2,
    const float* __restrict__ m2, const float* __restrict__ v2,
    __hip_bfloat16* __restrict__ out2b) {
  __shared__ float sI[57 * 57];
  int bid = blockIdx.x;            // NN*CMID = 512
  int n = bid >> 4, c = bid & 15;
  int tid = threadIdx.x;
  int lane = tid & 63, w = tid >> 6; // 8 waves

  // zero border row 0 and col 0 (interior fully overwritten below)
  if (tid < 57) { sI[tid] = 0.f; sI[tid * 57] = 0.f; }
  // float4 plane load (56 % 4 == 0 -> each float4 within one row)
  const float* src = out1 + ((size_t)n * CMID + c) * HW;
  for (int vdx = tid; vdx < HW / 4; vdx += 512) {
    int p = vdx * 4;
    int h = p / 56, wq = p - h * 56;
    f32x4 d = ((const f32x4*)src)[vdx];
    float* dst = &sI[(h + 1) * 57 + wq + 1];
    dst[0] = d.x; dst[1] = d.y; dst[2] = d.z; dst[3] = d.w;
  }
  __syncthreads();

  // row scans: wave w handles rows w, w+8, ... (shuffle inclusive scan)
  for (int r = w; r < 56; r += 8) {
    float* row = &sI[(r + 1) * 57 + 1];
    float vv = (lane < 56) ? row[lane] : 0.f;
#pragma unroll
    for (int d = 1; d < 64; d <<= 1) {
      float o = __shfl_up(vv, d, 64);
      if (lane >= d) vv += o;
    }
    if (lane < 56) row[lane] = vv;
  }
  __syncthreads();
  // col scans: stride 57 (odd) -> bank-conflict-free
  for (int cc = w; cc < 56; cc += 8) {
    float* col = &sI[57 + cc + 1];
    float vv = (lane < 56) ? col[lane * 57] : 0.f;
#pragma unroll
    for (int d = 1; d < 64; d <<= 1) {
      float o = __shfl_up(vv, d, 64);
      if (lane >= d) vv += o;
    }
    if (lane < 56) col[lane * 57] = vv;
  }
  __syncthreads();

  float pymn[NB], pymx[NB], pxmn[NB], pxmx[NB], pinv[NB], pbi[NB], prar[NB];
#pragma unroll
  for (int b = 0; b < NB; ++b) {
    int cb = c * NB + b;
    pymn[b] = y_min[cb]; pymx[b] = y_max[cb];
    pxmn[b] = x_min[cb]; pxmx[b] = x_max[cb];
    float inv = g2[cb] / sqrtf(v2[cb] + EPSB);
    pinv[b] = inv;
    pbi[b] = b2[cb] - m2[cb] * inv;
    prar[b] = 1.f / ((pymx[b] - pymn[b] + 1.f) * (pxmx[b] - pxmn[b] + 1.f));
  }
  __hip_bfloat16* dst0 = out2b + ((size_t)n * CBOX + c * NB) * HW;

  for (int p = tid; p < HW; p += 512) {
    int h = p / 56, wq = p - h * 56;
    float fh = (float)h, fw = (float)wq;
#pragma unroll
    for (int b = 0; b < NB; ++b) {
      float y1 = fminf(fmaxf(fh + pymn[b], 0.f), 56.f);
      float y2 = fminf(fmaxf(fh + pymx[b] + 1.f, 0.f), 56.f);
      float x1 = fminf(fmaxf(fw + pxmn[b], 0.f), 56.f);
      float x2 = fminf(fmaxf(fw + pxmx[b] + 1.f, 0.f), 56.f);
      float S = bilin(sI, y2, x2) - bilin(sI, y2, x1) - bilin(sI, y1, x2) + bilin(sI, y1, x1);
      float val = S * prar[b] * pinv[b] + pbi[b];
      dst0[(size_t)b * HW + p] = __float2bfloat16(fmaxf(val, 0.f));
    }
  }
}

// conv3 (64->256) via bf16 MFMA + BN3 + residual + ReLU.
// Block: 512 thr (8 waves), 64 pixels x 256 outputs. Wave w -> o in [w*32, w*32+32).
// w3 read as f32, converted to bf16 frags in-register (no prep kernel).
__global__ __launch_bounds__(512) void k3(
    const __hip_bfloat16* __restrict__ out2b,
    const float* __restrict__ w3,
    const float* __restrict__ g3, const float* __restrict__ b3,
    const float* __restrict__ m3, const float* __restrict__ v3,
    const float* __restrict__ x, float* __restrict__ out) {
  __shared__ __hip_bfloat16 T[64][72]; // [pix][k], 144B rows
  int bid = blockIdx.x;                // NN*49
  int n = bid / 49, hwb = (bid % 49) * 64;
  int tid = threadIdx.x;
  int l = tid & 63, w = tid >> 6;

  // stage out2 tile transposed: lane l = k-row, wave w = pixel group (8 pix)
  {
    const __hip_bfloat16* srcp = out2b + ((size_t)n * CBOX + l) * HW + hwb + w * 8;
    short8 v = *reinterpret_cast<const short8*>(srcp);
    const __hip_bfloat16* vp = (const __hip_bfloat16*)&v;
#pragma unroll
    for (int i = 0; i < 8; ++i) T[w * 8 + i][l] = vp[i];
  }

  // A-frags from f32 w3 [o][k], converted: lane l holds A[o0+(l&15)][k0+(l>>4)*8+j]
  short8 afrag[2][2];
#pragma unroll
  for (int ot = 0; ot < 2; ++ot)
#pragma unroll
    for (int kh = 0; kh < 2; ++kh) {
      int o = w * 32 + ot * 16 + (l & 15);
      int k0 = kh * 32 + (l >> 4) * 8;
      const float* wp = w3 + o * CBOX + k0;
      union { short8 s; __hip_bfloat16 h[8]; } u;
#pragma unroll
      for (int j = 0; j < 8; ++j) u.h[j] = __float2bfloat16(wp[j]);
      afrag[ot][kh] = u.s;
    }

  __syncthreads();

  short8 bfrag[4][2];
#pragma unroll
  for (int pt = 0; pt < 4; ++pt)
#pragma unroll
    for (int kh = 0; kh < 2; ++kh) {
      int pix = pt * 16 + (l & 15);
      int k0 = kh * 32 + (l >> 4) * 8;
      bfrag[pt][kh] = *reinterpret_cast<const short8*>(&T[pix][k0]);
    }

  f32x4 acc[2][4];
#pragma unroll
  for (int ot = 0; ot < 2; ++ot)
#pragma unroll
    for (int pt = 0; pt < 4; ++pt) acc[ot][pt] = (f32x4)(0.f);

#pragma unroll
  for (int ot = 0; ot < 2; ++ot)
#pragma unroll
    for (int pt = 0; pt < 4; ++pt) {
      acc[ot][pt] = __builtin_amdgcn_mfma_f32_16x16x32_bf16(
          afrag[ot][0], bfrag[pt][0], acc[ot][pt], 0, 0, 0);
      acc[ot][pt] = __builtin_amdgcn_mfma_f32_16x16x32_bf16(
          afrag[ot][1], bfrag[pt][1], acc[ot][pt], 0, 0, 0);
    }

  // epilogue: D row = o = o0 + (l>>4)*4 + j, col = pix = pt*16 + (l&15)
  size_t nbase = (size_t)n * COUT * HW + hwb;
#pragma unroll
  for (int ot = 0; ot < 2; ++ot) {
#pragma unroll
    for (int j = 0; j < 4; ++j) {
      int o = w * 32 + ot * 16 + (l >> 4) * 4 + j;
      float iv = g3[o] / sqrtf(v3[o] + EPSB);
      float bb = b3[o] - m3[o] * iv;
      size_t rowbase = nbase + (size_t)o * HW;
#pragma unroll
      for (int pt = 0; pt < 4; ++pt) {
        int pix = pt * 16 + (l & 15);
        float v = acc[ot][pt][j] * iv + bb + x[rowbase + pix];
        out[rowbase + pix] = fmaxf(v, 0.f);
      }
    }
  }
}

extern "C" void kernel_launch(void* const* d_in, const int* in_sizes, int n_in,
                              void* d_out, int out_size, void* d_ws, size_t ws_size,
                              hipStream_t stream) {
  const float* x   = (const float*)d_in[0];
  const float* w1  = (const float*)d_in[1];
  const float* g1  = (const float*)d_in[2];
  const float* b1  = (const float*)d_in[3];
  const float* m1  = (const float*)d_in[4];
  const float* v1  = (const float*)d_in[5];
  const float* ymn = (const float*)d_in[6];
  const float* ymx = (const float*)d_in[7];
  const float* xmn = (const float*)d_in[8];
  const float* xmx = (const float*)d_in[9];
  const float* g2  = (const float*)d_in[10];
  const float* b2  = (const float*)d_in[11];
  const float* m2  = (const float*)d_in[12];
  const float* v2  = (const float*)d_in[13];
  const float* w3  = (const float*)d_in[14];
  const float* g3  = (const float*)d_in[15];
  const float* b3  = (const float*)d_in[16];
  const float* m3  = (const float*)d_in[17];
  const float* v3  = (const float*)d_in[18];

  float* ws  = (float*)d_ws;
  float* out = (float*)d_out;
  __hip_bfloat16* out2b = (__hip_bfloat16*)(ws + WS_OUT2B);

  k1<<<NN * 49, 256, 0, stream>>>(x, w1, g1, b1, m1, v1, ws + WS_OUT1);
  k2<<<NN * CMID, 512, 0, stream>>>(ws + WS_OUT1, ymn, ymx, xmn, xmx,
                                    g2, b2, m2, v2, out2b);
  k3<<<NN * 49, 512, 0, stream>>>(out2b, w3, g3, b3, m3, v3, x, out);
}

// Round 4
// 81.497 us; speedup vs baseline: 1.3742x; 1.1057x over previous
//
#include <hip/hip_runtime.h>
#include <hip/hip_bf16.h>
#include <math.h>

#define EPSB 1e-5f

constexpr int NN = 32, CIN = 256, HH = 56, WW = 56, HW = HH * WW; // 3136
constexpr int CMID = 16, NB = 4, CBOX = 64, COUT = 256;

typedef __attribute__((ext_vector_type(8))) short short8;
typedef __attribute__((ext_vector_type(4))) float f32x4;

// workspace offsets (in floats)
constexpr size_t WS_OUT1  = 0;                                  // N*CMID*HW f32
constexpr size_t WS_OUT2B = WS_OUT1 + (size_t)NN * CMID * HW;   // N*64*HW bf16

// conv1 (256->16) + BN1 + ReLU via bf16 MFMA.
// Block: 256 thr (4 waves), tile = 64 px x 256 ci -> 16 c x 64 px.
// Wave w owns px [16w, 16w+16). K=256 in 8 MFMA steps.
__global__ __launch_bounds__(256) void k1(const float* __restrict__ x,
                                          const float* __restrict__ w1,
                                          const float* __restrict__ g1,
                                          const float* __restrict__ b1,
                                          const float* __restrict__ m1,
                                          const float* __restrict__ v1,
                                          float* __restrict__ out1) {
  __shared__ __hip_bfloat16 Xb[64][264]; // [px][ci], 528B rows (16B-aligned, bank-rotating)
  __shared__ __hip_bfloat16 Wb[16][264]; // [c][ci] folded w1*inv1
  int bid = blockIdx.x;                  // NN*49
  int n = bid / 49, hwb = (bid % 49) * 64;
  int tid = threadIdx.x;
  int l = tid & 63, w = tid >> 6;

  // stage Wb: thread t -> c = t>>4, k-range = (t&15)*16 .. +16
  {
    int c = tid >> 4, kb = (tid & 15) * 16;
    float inv = g1[c] / sqrtf(v1[c] + EPSB);
    const float* wp = w1 + c * CIN + kb;
#pragma unroll
    for (int j = 0; j < 16; ++j)
      Wb[c][kb + j] = __float2bfloat16(wp[j] * inv);
  }

  // stage Xb transposed: thread t -> px quad (t&15)*4, ci pair base (t>>4)*2
  {
    const float* xb = x + (size_t)n * CIN * HW + hwb;
    int pxq = (tid & 15) * 4;
    int cio = (tid >> 4) * 2;
#pragma unroll
    for (int p = 0; p < 8; ++p) {
      int ci = p * 32 + cio;
      f32x4 a = *reinterpret_cast<const f32x4*>(xb + (size_t)ci * HW + pxq);
      f32x4 b = *reinterpret_cast<const f32x4*>(xb + (size_t)(ci + 1) * HW + pxq);
#pragma unroll
      for (int j = 0; j < 4; ++j) {
        unsigned lo = (unsigned)__bfloat16_as_ushort(__float2bfloat16(a[j]));
        unsigned hi = (unsigned)__bfloat16_as_ushort(__float2bfloat16(b[j]));
        *reinterpret_cast<unsigned*>(&Xb[pxq + j][ci]) = lo | (hi << 16);
      }
    }
  }
  __syncthreads();

  // MFMA: A = Wb [c][k], B = Xb [k][px] (frag reads from [px][k] rows)
  int pix = 16 * w + (l & 15);
  f32x4 acc = (f32x4)(0.f);
#pragma unroll
  for (int kk = 0; kk < 8; ++kk) {
    int k0 = kk * 32 + (l >> 4) * 8;
    short8 afr = *reinterpret_cast<const short8*>(&Wb[l & 15][k0]);
    short8 bfr = *reinterpret_cast<const short8*>(&Xb[pix][k0]);
    acc = __builtin_amdgcn_mfma_f32_16x16x32_bf16(afr, bfr, acc, 0, 0, 0);
  }

  // epilogue: D row = c = (l>>4)*4 + j, col = pix
#pragma unroll
  for (int j = 0; j < 4; ++j) {
    int c = (l >> 4) * 4 + j;
    float inv = g1[c] / sqrtf(v1[c] + EPSB);
    float val = acc[j] + (b1[c] - m1[c] * inv);
    out1[((size_t)n * CMID + c) * HW + hwb + pix] = fmaxf(val, 0.f);
  }
}

__device__ __forceinline__ float bilin(const float* __restrict__ sI, float y, float x) {
  int iy = min((int)y, 55);
  int ix = min((int)x, 55);
  float ty = y - (float)iy;
  float tx = x - (float)ix;
  const float* r = sI + iy * 57 + ix;
  float a = r[0], b = r[1], cc = r[57], d = r[58];
  float g1v = a * (1.f - ty) + cc * ty;
  float g2v = b * (1.f - ty) + d * ty;
  return g1v * (1.f - tx) + g2v * tx;
}

// integral image (wave-parallel scans) + 4 boxes + BN2 + ReLU -> bf16.
__global__ __launch_bounds__(512) void k2(
    const float* __restrict__ out1,
    const float* __restrict__ y_min, const float* __restrict__ y_max,
    const float* __restrict__ x_min, const float* __restrict__ x_max,
    const float* __restrict__ g2, const float* __restrict__ b2,
    const float* __restrict__ m2, const float* __restrict__ v2,
    __hip_bfloat16* __restrict__ out2b) {
  __shared__ float sI[57 * 57];
  int bid = blockIdx.x;            // NN*CMID = 512
  int n = bid >> 4, c = bid & 15;
  int tid = threadIdx.x;
  int lane = tid & 63, w = tid >> 6; // 8 waves

  if (tid < 57) { sI[tid] = 0.f; sI[tid * 57] = 0.f; }
  const float* src = out1 + ((size_t)n * CMID + c) * HW;
  for (int vdx = tid; vdx < HW / 4; vdx += 512) {
    int p = vdx * 4;
    int h = p / 56, wq = p - h * 56;
    f32x4 d = ((const f32x4*)src)[vdx];
    float* dst = &sI[(h + 1) * 57 + wq + 1];
    dst[0] = d.x; dst[1] = d.y; dst[2] = d.z; dst[3] = d.w;
  }
  __syncthreads();

  for (int r = w; r < 56; r += 8) {
    float* row = &sI[(r + 1) * 57 + 1];
    float vv = (lane < 56) ? row[lane] : 0.f;
#pragma unroll
    for (int d = 1; d < 64; d <<= 1) {
      float o = __shfl_up(vv, d, 64);
      if (lane >= d) vv += o;
    }
    if (lane < 56) row[lane] = vv;
  }
  __syncthreads();
  for (int cc = w; cc < 56; cc += 8) {
    float* col = &sI[57 + cc + 1];
    float vv = (lane < 56) ? col[lane * 57] : 0.f;
#pragma unroll
    for (int d = 1; d < 64; d <<= 1) {
      float o = __shfl_up(vv, d, 64);
      if (lane >= d) vv += o;
    }
    if (lane < 56) col[lane * 57] = vv;
  }
  __syncthreads();

  float pymn[NB], pymx[NB], pxmn[NB], pxmx[NB], pinv[NB], pbi[NB], prar[NB];
#pragma unroll
  for (int b = 0; b < NB; ++b) {
    int cb = c * NB + b;
    pymn[b] = y_min[cb]; pymx[b] = y_max[cb];
    pxmn[b] = x_min[cb]; pxmx[b] = x_max[cb];
    float inv = g2[cb] / sqrtf(v2[cb] + EPSB);
    pinv[b] = inv;
    pbi[b] = b2[cb] - m2[cb] * inv;
    prar[b] = 1.f / ((pymx[b] - pymn[b] + 1.f) * (pxmx[b] - pxmn[b] + 1.f));
  }
  __hip_bfloat16* dst0 = out2b + ((size_t)n * CBOX + c * NB) * HW;

  for (int p = tid; p < HW; p += 512) {
    int h = p / 56, wq = p - h * 56;
    float fh = (float)h, fw = (float)wq;
#pragma unroll
    for (int b = 0; b < NB; ++b) {
      float y1 = fminf(fmaxf(fh + pymn[b], 0.f), 56.f);
      float y2 = fminf(fmaxf(fh + pymx[b] + 1.f, 0.f), 56.f);
      float x1 = fminf(fmaxf(fw + pxmn[b], 0.f), 56.f);
      float x2 = fminf(fmaxf(fw + pxmx[b] + 1.f, 0.f), 56.f);
      float S = bilin(sI, y2, x2) - bilin(sI, y2, x1) - bilin(sI, y1, x2) + bilin(sI, y1, x1);
      float val = S * prar[b] * pinv[b] + pbi[b];
      dst0[(size_t)b * HW + p] = __float2bfloat16(fmaxf(val, 0.f));
    }
  }
}

// conv3 (64->256) via bf16 MFMA + BN3 + residual + ReLU.
__global__ __launch_bounds__(512) void k3(
    const __hip_bfloat16* __restrict__ out2b,
    const float* __restrict__ w3,
    const float* __restrict__ g3, const float* __restrict__ b3,
    const float* __restrict__ m3, const float* __restrict__ v3,
    const float* __restrict__ x, float* __restrict__ out) {
  __shared__ __hip_bfloat16 T[64][72]; // [pix][k], 144B rows
  int bid = blockIdx.x;                // NN*49
  int n = bid / 49, hwb = (bid % 49) * 64;
  int tid = threadIdx.x;
  int l = tid & 63, w = tid >> 6;

  {
    const __hip_bfloat16* srcp = out2b + ((size_t)n * CBOX + l) * HW + hwb + w * 8;
    short8 v = *reinterpret_cast<const short8*>(srcp);
    const __hip_bfloat16* vp = (const __hip_bfloat16*)&v;
#pragma unroll
    for (int i = 0; i < 8; ++i) T[w * 8 + i][l] = vp[i];
  }

  short8 afrag[2][2];
#pragma unroll
  for (int ot = 0; ot < 2; ++ot)
#pragma unroll
    for (int kh = 0; kh < 2; ++kh) {
      int o = w * 32 + ot * 16 + (l & 15);
      int k0 = kh * 32 + (l >> 4) * 8;
      const float* wp = w3 + o * CBOX + k0;
      union { short8 s; __hip_bfloat16 h[8]; } u;
#pragma unroll
      for (int j = 0; j < 8; ++j) u.h[j] = __float2bfloat16(wp[j]);
      afrag[ot][kh] = u.s;
    }

  __syncthreads();

  short8 bfrag[4][2];
#pragma unroll
  for (int pt = 0; pt < 4; ++pt)
#pragma unroll
    for (int kh = 0; kh < 2; ++kh) {
      int pix = pt * 16 + (l & 15);
      int k0 = kh * 32 + (l >> 4) * 8;
      bfrag[pt][kh] = *reinterpret_cast<const short8*>(&T[pix][k0]);
    }

  f32x4 acc[2][4];
#pragma unroll
  for (int ot = 0; ot < 2; ++ot)
#pragma unroll
    for (int pt = 0; pt < 4; ++pt) acc[ot][pt] = (f32x4)(0.f);

#pragma unroll
  for (int ot = 0; ot < 2; ++ot)
#pragma unroll
    for (int pt = 0; pt < 4; ++pt) {
      acc[ot][pt] = __builtin_amdgcn_mfma_f32_16x16x32_bf16(
          afrag[ot][0], bfrag[pt][0], acc[ot][pt], 0, 0, 0);
      acc[ot][pt] = __builtin_amdgcn_mfma_f32_16x16x32_bf16(
          afrag[ot][1], bfrag[pt][1], acc[ot][pt], 0, 0, 0);
    }

  size_t nbase = (size_t)n * COUT * HW + hwb;
#pragma unroll
  for (int ot = 0; ot < 2; ++ot) {
#pragma unroll
    for (int j = 0; j < 4; ++j) {
      int o = w * 32 + ot * 16 + (l >> 4) * 4 + j;
      float iv = g3[o] / sqrtf(v3[o] + EPSB);
      float bb = b3[o] - m3[o] * iv;
      size_t rowbase = nbase + (size_t)o * HW;
#pragma unroll
      for (int pt = 0; pt < 4; ++pt) {
        int pix = pt * 16 + (l & 15);
        float v = acc[ot][pt][j] * iv + bb + x[rowbase + pix];
        out[rowbase + pix] = fmaxf(v, 0.f);
      }
    }
  }
}

extern "C" void kernel_launch(void* const* d_in, const int* in_sizes, int n_in,
                              void* d_out, int out_size, void* d_ws, size_t ws_size,
                              hipStream_t stream) {
  const float* x   = (const float*)d_in[0];
  const float* w1  = (const float*)d_in[1];
  const float* g1  = (const float*)d_in[2];
  const float* b1  = (const float*)d_in[3];
  const float* m1  = (const float*)d_in[4];
  const float* v1  = (const float*)d_in[5];
  const float* ymn = (const float*)d_in[6];
  const float* ymx = (const float*)d_in[7];
  const float* xmn = (const float*)d_in[8];
  const float* xmx = (const float*)d_in[9];
  const float* g2  = (const float*)d_in[10];
  const float* b2  = (const float*)d_in[11];
  const float* m2  = (const float*)d_in[12];
  const float* v2  = (const float*)d_in[13];
  const float* w3  = (const float*)d_in[14];
  const float* g3  = (const float*)d_in[15];
  const float* b3  = (const float*)d_in[16];
  const float* m3  = (const float*)d_in[17];
  const float* v3  = (const float*)d_in[18];

  float* ws  = (float*)d_ws;
  float* out = (float*)d_out;
  __hip_bfloat16* out2b = (__hip_bfloat16*)(ws + WS_OUT2B);

  k1<<<NN * 49, 256, 0, stream>>>(x, w1, g1, b1, m1, v1, ws + WS_OUT1);
  k2<<<NN * CMID, 512, 0, stream>>>(ws + WS_OUT1, ymn, ymx, xmn, xmx,
                                    g2, b2, m2, v2, out2b);
  k3<<<NN * 49, 512, 0, stream>>>(out2b, w3, g3, b3, m3, v3, x, out);
}